// Round 13
// baseline (412.362 us; speedup 1.0000x reference)
//
#include <hip/hip_runtime.h>
#include <stdint.h>

#define BN 4
#define SN 4096
#define EN 256
#define PN 32
#define FN 1024
#define BS (BN*SN)   // 16384
#define PAUG 64      // 32 xs chans + aug (+ zero pad to 64)

typedef uint16_t bf16_t;
typedef short v4s  __attribute__((ext_vector_type(4)));
typedef short v8s  __attribute__((ext_vector_type(8)));
typedef __bf16 bf16x8 __attribute__((ext_vector_type(8)));
typedef float v4f   __attribute__((ext_vector_type(4)));
typedef float v16f  __attribute__((ext_vector_type(16)));

#define MFMA16(a,b,c) __builtin_amdgcn_mfma_f32_16x16x32_bf16(a,b,c,0,0,0)
#define MFMA32(a,b,c) __builtin_amdgcn_mfma_f32_32x32x16_bf16(a,b,c,0,0,0)

__device__ __forceinline__ float b2f(bf16_t x){
    uint32_t u = ((uint32_t)x) << 16; float f; __builtin_memcpy(&f, &u, 4); return f;
}
__device__ __forceinline__ bf16_t f2b(float f){
    uint32_t u; __builtin_memcpy(&u, &f, 4);
    u += 0x7FFFu + ((u >> 16) & 1u);           // RNE
    return (bf16_t)(u >> 16);
}
__device__ __forceinline__ bf16x8 ldb8(const bf16_t* p){
    v8s r = *(const v8s*)p; return __builtin_bit_cast(bf16x8, r);
}
// 8-B-aligned load pair (for LDS rows with odd 8-B stride -> 2-way-free banks)
__device__ __forceinline__ bf16x8 ldb8u(const bf16_t* p){
    v4s lo = *(const v4s*)p;
    v4s hi = *(const v4s*)(p + 4);
    v8s r = __builtin_shufflevector(lo, hi, 0,1,2,3,4,5,6,7);
    return __builtin_bit_cast(bf16x8, r);
}
__device__ __forceinline__ float ldsc(const float* p){ return *p; }
__device__ __forceinline__ float ldsc(const bf16_t* p){ return b2f(*p); }
__device__ __forceinline__ void stsc(float* p, float v){ *p = v; }
__device__ __forceinline__ void stsc(bf16_t* p, float v){ *p = f2b(v); }

#if __has_builtin(__builtin_amdgcn_exp2f)
__device__ __forceinline__ float fexp2(float x){ return __builtin_amdgcn_exp2f(x); }
#else
__device__ __forceinline__ float fexp2(float x){ return exp2f(x); }
#endif

#if __has_builtin(__builtin_amdgcn_cvt_pk_bf16_f32)
typedef __bf16 bf16x2 __attribute__((ext_vector_type(2)));
__device__ __forceinline__ uint32_t pkbf16(float a, float b){
    bf16x2 r = __builtin_amdgcn_cvt_pk_bf16_f32(a, b);
    return __builtin_bit_cast(uint32_t, r);
}
#else
__device__ __forceinline__ uint32_t pkbf16(float a, float b){
    return (uint32_t)f2b(a) | ((uint32_t)f2b(b) << 16);
}
#endif

typedef const __attribute__((address_space(1))) uint32_t* glds_gp;
typedef __attribute__((address_space(3))) uint32_t* glds_lp;
__device__ __forceinline__ void glds16(const bf16_t* g, bf16_t* l){
    __builtin_amdgcn_global_load_lds((glds_gp)g, (glds_lp)l, 16, 0, 0);
}

// ---------------------------------------------------------------------------
// prep: (a) src fp32->bf16, (b) weight cvts (Wo -> MFMA16-B FRAGMENT order),
// (c) posxs. One launch.
// ---------------------------------------------------------------------------
__global__ __launch_bounds__(256) void prep_kernel(
    const float* __restrict__ src, bf16_t* __restrict__ srcb,
    const float* __restrict__ Wv, bf16_t* __restrict__ Wvb,
    const float* __restrict__ Wo, bf16_t* __restrict__ Wob,
    const float* __restrict__ W1, bf16_t* __restrict__ W1b,
    const float* __restrict__ W2, bf16_t* __restrict__ W2b,
    const float* __restrict__ pos, const float* __restrict__ Wp,
    const float* __restrict__ bp,  const float* __restrict__ lsp,
    bf16_t* __restrict__ xk, bf16_t* __restrict__ xq)
{
    __shared__ float Wsh[PN*PN];
    __shared__ float bsh[PN];
    int bid = blockIdx.x;
    int tid = threadIdx.x;

    if (bid < 4736){
        const float* sp; bf16_t* dp; int off;
        if (bid < 4096){ sp = src; dp = srcb; off = (bid*256 + tid)*4; }
        else {
            int i = ((bid - 4096)*256 + tid)*4;
            if      (i <  65536){ sp=Wv; dp=Wvb; off=i; }
            else if (i < 131072){
                // Wo -> fragment order
                int idx = i - 65536;
                float4 f = *(const float4*)(Wo + idx);
                v4s o;
                o.x = (short)f2b(f.x); o.y = (short)f2b(f.y);
                o.z = (short)f2b(f.z); o.w = (short)f2b(f.w);
                int n = idx >> 8, k = idx & 255;
                int dst = (((n>>4)*8 + (k>>5))*64 + (((k>>3)&3)*16 + (n&15)))*8 + (k&7);
                *(v4s*)(Wob + dst) = o;
                return;
            }
            else if (i < 393216){ sp=W1; dp=W1b; off=i-131072; }
            else                { sp=W2; dp=W2b; off=i-393216; }
        }
        float4 f = *(const float4*)(sp + off);
        v4s o;
        o.x = (short)f2b(f.x); o.y = (short)f2b(f.y);
        o.z = (short)f2b(f.z); o.w = (short)f2b(f.w);
        *(v4s*)(dp + off) = o;
        return;
    }

    int pb = bid - 4736;          // 0..63
    int b  = pb >> 4;
    int s  = (pb & 15)*256 + tid;

    for (int i = tid; i < PN*PN; i += 256) Wsh[i] = Wp[i];
    if (tid < PN) bsh[tid] = bp[tid];
    __syncthreads();

    float inv_ls = 1.0f / lsp[0];
    const float c1f = 1.4426950408889634f;

    float col[PN];
    #pragma unroll
    for (int p = 0; p < PN; p++) col[p] = pos[((size_t)b*PN + p)*SN + s];

    uint16_t xb[PN], qb[PN];
    float sq = 0.f;
    #pragma unroll 4
    for (int o = 0; o < PN; o++){
        float pe = bsh[o];
        #pragma unroll
        for (int p = 0; p < PN; p++) pe += col[p] * Wsh[o*PN + p];
        float pv = pe * inv_ls;
        uint16_t h = f2b(pv);
        xb[o] = h;
        qb[o] = f2b(c1f * pv);
        float xr = b2f(h);
        sq += xr * xr;
    }

    size_t base = ((size_t)b*SN + s) * PAUG;
    v8s pk[8];
    #pragma unroll
    for (int c = 0; c < 4; c++)
        #pragma unroll
        for (int j = 0; j < 8; j++) ((short*)&pk[c])[j] = (short)xb[c*8 + j];
    #pragma unroll
    for (int c = 4; c < 8; c++)
        #pragma unroll
        for (int j = 0; j < 8; j++) ((short*)&pk[c])[j] = 0;
    ((short*)&pk[4])[0] = (short)f2b(-0.5f * sq);
    ((short*)&pk[4])[1] = (short)0x3F80;   // 1.0
    #pragma unroll
    for (int c = 0; c < 8; c++) *(v8s*)(xk + base + c*8) = pk[c];

    #pragma unroll
    for (int c = 0; c < 4; c++)
        #pragma unroll
        for (int j = 0; j < 8; j++) ((short*)&pk[c])[j] = (short)qb[c*8 + j];
    ((short*)&pk[4])[0] = (short)f2b(c1f);
    ((short*)&pk[4])[1] = (short)f2b(-0.5f * sq * c1f);
    #pragma unroll
    for (int c = 0; c < 8; c++) *(v8s*)(xq + base + c*8) = pk[c];
}

// ---------------------------------------------------------------------------
// gemm_t (64x64 tile) -- kept ONLY for the Wv projection (EPI 3: fragment-
// ordered V store, lane-major coalesced epilogue).
// ---------------------------------------------------------------------------
template<int EPI, typename OutT>
__global__ __launch_bounds__(256) void gemm_t(
    const bf16_t* __restrict__ A, const bf16_t* __restrict__ W,
    const float* __restrict__ bias, OutT* __restrict__ out,
    bf16_t* __restrict__ vt, int N, int K)
{
    __shared__ __align__(16) bf16_t At[2][4096];   // 2 x 8 KB
    __shared__ __align__(16) bf16_t Wt[2][4096];   // 2 x 8 KB
    int tid = threadIdx.x;
    int lane = tid & 63, wv = tid >> 6, col = lane & 15, quad = lane >> 4;
    int m0 = blockIdx.x * 64, n0 = blockIdx.y * 64;
    int nck = K >> 6;

    int srow = tid >> 3;                      // 0..31
    int spc  = (tid & 7) ^ (srow & 7);        // swizzled source piece
    const bf16_t* asrc = A + (size_t)(m0 + srow)*K + spc*8;
    const bf16_t* wsrc = W + (size_t)(n0 + srow)*K + spc*8;

    v4f acc[4];
    #pragma unroll
    for (int t = 0; t < 4; t++) acc[t] = (v4f){0.f,0.f,0.f,0.f};

    // stage chunk 0
    glds16(asrc, &At[0][tid*8]);
    glds16(asrc + (size_t)32*K, &At[0][2048 + tid*8]);
    glds16(wsrc, &Wt[0][tid*8]);
    glds16(wsrc + (size_t)32*K, &Wt[0][2048 + tid*8]);
    __syncthreads();

    for (int c = 0; c < nck; c++){
        int cb = c & 1;
        if (c + 1 < nck){
            glds16(asrc + (c+1)*64, &At[cb^1][tid*8]);
            glds16(asrc + (size_t)32*K + (c+1)*64, &At[cb^1][2048 + tid*8]);
            glds16(wsrc + (c+1)*64, &Wt[cb^1][tid*8]);
            glds16(wsrc + (size_t)32*K + (c+1)*64, &Wt[cb^1][2048 + tid*8]);
        }
        #pragma unroll
        for (int kc = 0; kc < 2; kc++){
            int pc = ((kc*4 + quad) ^ (col & 7)) * 8;
            bf16x8 a = ldb8(&At[cb][(wv*16 + col)*64 + pc]);
            #pragma unroll
            for (int t = 0; t < 4; t++){
                bf16x8 b = ldb8(&Wt[cb][(t*16 + col)*64 + pc]);
                acc[t] = MFMA16(a, b, acc[t]);
            }
        }
        __syncthreads();
    }

    float bfv[4];
    #pragma unroll
    for (int t = 0; t < 4; t++) bfv[t] = bias[n0 + t*16 + col];

    if constexpr (EPI == 3){
        __shared__ uint16_t Tsh[64*74];
        #pragma unroll
        for (int r = 0; r < 4; r++)
            #pragma unroll
            for (int t = 0; t < 4; t++)
                Tsh[(wv*16 + quad*4 + r)*74 + t*16 + col] = f2b(acc[t][r] + bfv[t]);
        __syncthreads();
        int e = tid & 63, sc = tid >> 6;       // lane-major e (coalesced)
        int b = m0 >> 12;
        int sbat = m0 & (SN-1);
        int eb   = (n0 + e) >> 5;
        int l31e = (n0 + e) & 31;
        int k16  = (sbat >> 4) + sc;
        v8s p0, p1;
        #pragma unroll
        for (int i = 0; i < 8; i++) ((short*)&p0)[i] = (short)Tsh[(sc*16 + i)*74 + e];
        #pragma unroll
        for (int i = 0; i < 8; i++) ((short*)&p1)[i] = (short)Tsh[(sc*16 + 8 + i)*74 + e];
        bf16_t* dst = vt + ((((size_t)b*8 + eb)*256 + k16)*64 + l31e)*8;
        *(v8s*)dst = p0;              // half 0 (keys s&15 in 0..7)
        *(v8s*)(dst + 256) = p1;      // half 1 (keys s&15 in 8..15), +32 lanes
    } else {
        #pragma unroll
        for (int r = 0; r < 4; r++){
            int row = m0 + wv*16 + quad*4 + r;
            #pragma unroll
            for (int t = 0; t < 4; t++){
                float y = acc[t][r] + bfv[t];
                if constexpr (EPI == 1) y = fmaxf(y, 0.f);
                stsc(out + (size_t)row*N + n0 + t*16 + col, y);
            }
        }
    }
}

// ---------------------------------------------------------------------------
// ffn_ln v2 (verified round 12): out = LN2( relu(x@W1^T+b1) @ W2^T + b2 + x ).
// 32 rows/block, grid 512 (2 blocks/CU), single-buffered weight chunks.
// ---------------------------------------------------------------------------
__global__ __launch_bounds__(512, 4) void ffn_ln_kernel(
    const bf16_t* __restrict__ x,  const bf16_t* __restrict__ W1b,
    const float* __restrict__ b1,  const bf16_t* __restrict__ W2b,
    const float* __restrict__ b2,  const float* __restrict__ gamma,
    const float* __restrict__ beta, float* __restrict__ out)
{
    __shared__ __align__(16) bf16_t W1c[16384];  // 32 KB [kgrp s][64 h][8 pc]
    __shared__ __align__(16) bf16_t W2c[16384];  // 32 KB [ngrp s2][64 n][8 pc]
    __shared__ __align__(16) bf16_t Hs[32*68];   // 4.25 KB
    __shared__ float b1sh[1024];                 // 4 KB
    __shared__ float lnb[4][32][2];              // 1 KB

    int tid  = threadIdx.x;
    int lane = tid & 63;
    int wv   = tid >> 6;         // 0..7
    int col  = lane & 15;
    int quad = lane >> 4;
    int mw   = wv >> 2;          // 0..1 -> rows mw*16..+16
    int nw   = wv & 3;           // 0..3
    int m0   = blockIdx.x * 32;

    b1sh[tid]       = b1[tid];
    b1sh[512 + tid] = b1[512 + tid];

    const bf16_t* xrow = x + (size_t)(m0 + mw*16 + col)*EN + quad*8;
    bf16x8 xr[8];
    #pragma unroll
    for (int kk = 0; kk < 8; kk++) xr[kk] = ldb8(xrow + kk*32);

    float b2v[4], gv[4], bev[4];
    #pragma unroll
    for (int t2 = 0; t2 < 4; t2++){
        int nn = nw*64 + t2*16 + col;
        b2v[t2] = b2[nn]; gv[t2] = gamma[nn]; bev[t2] = beta[nn];
    }

    v4f acc[4];
    #pragma unroll
    for (int t2 = 0; t2 < 4; t2++) acc[t2] = (v4f){0.f,0.f,0.f,0.f};

    int wr  = tid >> 3;          // 0..63
    int pp  = tid & 7;
    int swz = (pp ^ (wr & 7)) * 8;

    #pragma unroll 1
    for (int c = 0; c < 16; c++){
        #pragma unroll
        for (int s = 0; s < 4; s++)
            glds16(W1b + (size_t)(c*64 + wr)*256 + s*64 + swz,
                   &W1c[s*4096 + tid*8]);
        #pragma unroll
        for (int s2 = 0; s2 < 4; s2++)
            glds16(W2b + (size_t)(s2*64 + wr)*1024 + c*64 + swz,
                   &W2c[s2*4096 + tid*8]);
        asm volatile("s_waitcnt vmcnt(0)" ::: "memory");
        __builtin_amdgcn_s_barrier();
        __builtin_amdgcn_sched_barrier(0);

        int hl = nw*16 + col;
        v4f hacc = (v4f){0.f,0.f,0.f,0.f};
        #pragma unroll
        for (int kk = 0; kk < 8; kk++){
            bf16x8 b = ldb8(&W1c[(kk>>1)*4096 + hl*64
                             + ((((kk&1)*4 + quad) ^ (hl & 7))*8)]);
            hacc = MFMA16(xr[kk], b, hacc);
        }
        float bb = b1sh[c*64 + hl];
        #pragma unroll
        for (int r = 0; r < 4; r++)
            Hs[(mw*16 + quad*4 + r)*68 + hl] = f2b(fmaxf(hacc[r] + bb, 0.f));
        asm volatile("s_waitcnt lgkmcnt(0)" ::: "memory");
        __builtin_amdgcn_s_barrier();
        __builtin_amdgcn_sched_barrier(0);

        #pragma unroll
        for (int kk2 = 0; kk2 < 2; kk2++){
            bf16x8 a2 = ldb8u(&Hs[(mw*16 + col)*68 + kk2*32 + quad*8]);
            #pragma unroll
            for (int t2 = 0; t2 < 4; t2++){
                int nn = nw*64 + t2*16 + col;
                bf16x8 bfr = ldb8(&W2c[(nn>>6)*4096 + (nn&63)*64
                                  + (((kk2*4 + quad) ^ (col & 7))*8)]);
                acc[t2] = MFMA16(a2, bfr, acc[t2]);
            }
        }
        asm volatile("s_waitcnt lgkmcnt(0)" ::: "memory");
        __builtin_amdgcn_s_barrier();
    }

    // ---- fused LN2 epilogue ----
    float v[4][4];
    float s1[4], s2[4];
    #pragma unroll
    for (int r = 0; r < 4; r++){ s1[r] = 0.f; s2[r] = 0.f; }
    #pragma unroll
    for (int r = 0; r < 4; r++){
        int row = m0 + mw*16 + quad*4 + r;
        #pragma unroll
        for (int t2 = 0; t2 < 4; t2++){
            int nn = nw*64 + t2*16 + col;
            float xv = acc[t2][r] + b2v[t2] + b2f(x[(size_t)row*EN + nn]);
            v[t2][r] = xv; s1[r] += xv; s2[r] += xv*xv;
        }
    }
    #pragma unroll
    for (int r = 0; r < 4; r++){
        #pragma unroll
        for (int m = 1; m <= 8; m <<= 1){
            s1[r] += __shfl_xor(s1[r], m);
            s2[r] += __shfl_xor(s2[r], m);
        }
    }
    if (col == 0){
        #pragma unroll
        for (int r = 0; r < 4; r++){
            int rl = mw*16 + quad*4 + r;
            lnb[nw][rl][0] = s1[r];
            lnb[nw][rl][1] = s2[r];
        }
    }
    __syncthreads();
    #pragma unroll
    for (int r = 0; r < 4; r++){
        int rl  = mw*16 + quad*4 + r;
        int row = m0 + rl;
        float S1 = lnb[0][rl][0] + lnb[1][rl][0] + lnb[2][rl][0] + lnb[3][rl][0];
        float S2 = lnb[0][rl][1] + lnb[1][rl][1] + lnb[2][rl][1] + lnb[3][rl][1];
        float mu = S1 * (1.f/256.f);
        float rs = rsqrtf(S2 * (1.f/256.f) - mu*mu + 1e-5f);
        #pragma unroll
        for (int t2 = 0; t2 < 4; t2++){
            int nn = nw*64 + t2*16 + col;
            out[(size_t)row*EN + nn] = (v[t2][r] - mu)*rs*gv[t2] + bev[t2];
        }
    }
}

// ---------------------------------------------------------------------------
// Attention round 20: PRODUCER/CONSUMER wave specialization.
// Waves 0-3 (QK): each computes weights for 64 keys of chunk it -> Wtb[it&1]
//   (2 kf-halves of 2x16 keys; 32 MFMA16 + exp per chunk).
// Waves 4-7 (PV): each owns 64 e-cols; lag-1: consumes Wtb[(it-1)&1] with
//   register-prefetched V frags vrA/vrB (issued previous iteration, in
//   flight across the raw barrier). af[4] LDS reads shared across both
//   e-groups. 17 iterations, ONE raw barrier each (lgkmcnt only).
// Parity safety: PV(it-1) reads (it-1)&1, QK(it) writes it&1 (disjoint);
// parity reuse by QK(it+1) is fenced by barrier(it) which drains PV reads.
// Epilogue: den (QK waves) -> dent; Osh written by PV waves; all-wave
// Wo+res+LN1 (verified round-11 code).
// ---------------------------------------------------------------------------
__global__ __launch_bounds__(512, 2) void attn_kernel(
    const bf16_t* __restrict__ xk, const bf16_t* __restrict__ xq,
    const bf16_t* __restrict__ vf, const float* __restrict__ osp,
    const bf16_t* __restrict__ wof, const float* __restrict__ bo,
    const bf16_t* __restrict__ res, const float* __restrict__ gamma,
    const float* __restrict__ beta, bf16_t* __restrict__ out)
{
    __shared__ __align__(16) bf16_t Wtb[2][64*260];   // 65 KB
    __shared__ __align__(16) bf16_t Qs[64*64];        // 8 KB
    __shared__ __align__(16) bf16_t Osh[64*256];      // 32 KB (O tile, swizzled)
    __shared__ float densh[4][64];                    // 1 KB
    __shared__ float dent[64];
    __shared__ float lnw[8][64][2];                   // 4 KB

    int tid  = threadIdx.x;
    int lane = tid & 63;
    int wv   = tid >> 6;          // 0..7
    int col  = lane & 15;
    int quad = lane >> 4;
    int l31  = lane & 31;
    int half = lane >> 5;
    int sub  = wv & 3;            // role-local wave id

    int bid = blockIdx.x;                    // 0..255
    int b   = (bid & 7) >> 1;
    int qi  = ((bid >> 3) << 1) | (bid & 1); // 0..63
    int q0  = qi * 64;

    float k2 = 1.4426950408889634f * osp[0];

    const bf16_t* xkb = xk + (size_t)b * SN * PAUG;
    const bf16_t* xqb = xq + (size_t)b * SN * PAUG;
    // PV wave sub owns e-cols [sub*64, sub*64+64): two e-groups (eb)
    const bf16_t* vfb0 = vf + (((size_t)b*8 + sub*2 + 0)*256)*512 + lane*8;
    const bf16_t* vfb1 = vf + (((size_t)b*8 + sub*2 + 1)*256)*512 + lane*8;

    // stage Q tile: piece-swizzled SOURCE, linear dest
    {
        int qrow = tid >> 3;                 // 0..63
        int qpc  = (tid & 7) ^ (qrow & 7);
        glds16(xqb + (size_t)(q0 + qrow)*PAUG + qpc*8, &Qs[tid*8]);
    }

    v16f acc[2][2];                // [eg][qg] (PV waves)
    #pragma unroll
    for (int eg = 0; eg < 2; eg++)
        #pragma unroll
        for (int qg = 0; qg < 2; qg++)
            #pragma unroll
            for (int i = 0; i < 16; i++) acc[eg][qg][i] = 0.f;
    bf16x8 vrA[16], vrB[16];       // V frags for eg0/eg1 (PV waves)
    float den[4] = {0.f, 0.f, 0.f, 0.f};
    const v4f zero = (v4f){0.f,0.f,0.f,0.f};

    __syncthreads();   // Qs staged (one-time full drain)

    #pragma unroll 1
    for (int it = 0; it <= 16; it++){
        if (wv < 4){
            // ---------- QK producer: weights for keys [sub*64, sub*64+64) ----
            if (it < 16){
                int cb = it & 1;
                #pragma unroll
                for (int hh = 0; hh < 2; hh++){
                    bf16x8 kfh[2][2];
                    #pragma unroll
                    for (int kg2 = 0; kg2 < 2; kg2++){
                        const bf16_t* kr = xkb
                            + (size_t)(it*256 + sub*64 + (hh*2 + kg2)*16 + col)*PAUG
                            + quad*8;
                        kfh[kg2][0] = ldb8(kr);
                        kfh[kg2][1] = ldb8(kr + 32);
                    }
                    #pragma unroll
                    for (int qg = 0; qg < 2; qg++){
                        #pragma unroll
                        for (int g2 = 0; g2 < 2; g2++){
                            int qr = qg*32 + g2*16 + col;
                            bf16x8 qa = ldb8(&Qs[qr*64 + ((quad    ) ^ (col & 7))*8]);
                            bf16x8 qb = ldb8(&Qs[qr*64 + ((4 + quad) ^ (col & 7))*8]);
                            #pragma unroll
                            for (int kg2 = 0; kg2 < 2; kg2++){
                                v4f st = MFMA16(kfh[kg2][0], qa, zero);
                                st = MFMA16(kfh[kg2][1], qb, st);
                                #pragma unroll
                                for (int rp = 0; rp < 2; rp++){
                                    float w0 = fexp2(fmaf(k2, fexp2(st[rp*2+0]), -k2));
                                    float w1 = fexp2(fmaf(k2, fexp2(st[rp*2+1]), -k2));
                                    den[qg*2+g2] += w0 + w1;
                                    *(uint32_t*)&Wtb[cb][qr*260 + sub*64
                                        + (hh*2+kg2)*16 + quad*4 + rp*2]
                                        = pkbf16(w0, w1);
                                }
                            }
                        }
                    }
                }
            }
        } else {
            // ---------- PV consumer: chunk it-1 from Wtb[(it-1)&1] ----------
            if (it >= 1){
                int par = (it - 1) & 1;
                #pragma unroll
                for (int qg = 0; qg < 2; qg++){
                    #pragma unroll
                    for (int sk4 = 0; sk4 < 4; sk4++){
                        bf16x8 af[4];
                        #pragma unroll
                        for (int j = 0; j < 4; j++)
                            af[j] = ldb8u(&Wtb[par][(qg*32 + l31)*260
                                          + (sk4*4 + j)*16 + half*8]);
                        #pragma unroll
                        for (int j = 0; j < 4; j++){
                            acc[0][qg] = MFMA32(af[j], vrA[sk4*4 + j], acc[0][qg]);
                            acc[1][qg] = MFMA32(af[j], vrB[sk4*4 + j], acc[1][qg]);
                        }
                    }
                }
            }
            if (it < 16){
                // prefetch V frags for chunk it (consumed next iteration;
                // in flight across the raw barrier)
                #pragma unroll
                for (int sk = 0; sk < 16; sk++)
                    vrA[sk] = ldb8(vfb0 + (size_t)(it*16 + sk)*512);
                #pragma unroll
                for (int sk = 0; sk < 16; sk++)
                    vrB[sk] = ldb8(vfb1 + (size_t)(it*16 + sk)*512);
            }
        }
        asm volatile("s_waitcnt lgkmcnt(0)" ::: "memory");
        __builtin_amdgcn_s_barrier();
        __builtin_amdgcn_sched_barrier(0);
    }

    // ---- hoist Wo b0-set fragment loads (L2 latency hides under den+Osh) ----
    bf16x8 wf0[8];
    #pragma unroll
    for (int kc = 0; kc < 8; kc++)
        wf0[kc] = ldb8(wof + (size_t)(((wv*2+0)*8 + kc)*64 + lane)*8);

    // ---- den reduce (QK waves hold den) ----
    #pragma unroll
    for (int d = 0; d < 4; d++){
        den[d] += __shfl_xor(den[d], 16);
        den[d] += __shfl_xor(den[d], 32);
    }
    if (wv < 4 && lane < 16){
        #pragma unroll
        for (int qg = 0; qg < 2; qg++)
            #pragma unroll
            for (int g2 = 0; g2 < 2; g2++)
                densh[wv][qg*32 + g2*16 + lane] = den[qg*2+g2];
    }
    __syncthreads();
    if (tid < 64){
        float s = densh[0][tid] + densh[1][tid] + densh[2][tid] + densh[3][tid];
        dent[tid] = 1.f / s;
    }
    __syncthreads();

    // ---- O -> LDS (PV waves; write-side XOR piece swizzle) ----
    if (wv >= 4){
        #pragma unroll
        for (int eg = 0; eg < 2; eg++){
            #pragma unroll
            for (int qg = 0; qg < 2; qg++){
                #pragma unroll
                for (int rg = 0; rg < 16; rg++){
                    int qrow = qg*32 + (rg & 3) + 8*(rg >> 2) + 4*half;
                    int e = sub*64 + eg*32 + l31;
                    int g = e >> 3;
                    Osh[qrow*256 + ((g ^ (qrow & 7))*8) + (e & 7)]
                        = f2b(acc[eg][qg][rg] * dent[qrow]);
                }
            }
        }
    }
    __syncthreads();

    // ---- y1 = O @ Wo^T : wave wv -> n-slice [wv*32, wv*32+32), K=256 ----
    v4f y[4][2];
    #pragma unroll
    for (int qg = 0; qg < 4; qg++)
        #pragma unroll
        for (int t = 0; t < 2; t++) y[qg][t] = (v4f){0.f,0.f,0.f,0.f};

    #pragma unroll
    for (int kc = 0; kc < 8; kc++){
        bf16x8 b1 = ldb8(wof + (size_t)(((wv*2+1)*8 + kc)*64 + lane)*8);
        #pragma unroll
        for (int qg = 0; qg < 4; qg++){
            bf16x8 a = ldb8(&Osh[(qg*16 + col)*256 + (((kc*4 + quad) ^ (col & 7))*8)]);
            y[qg][0] = MFMA16(a, wf0[kc], y[qg][0]);
            y[qg][1] = MFMA16(a, b1, y[qg][1]);
        }
    }

    // ---- bias + residual + LN1 partials ----
    size_t growb = (size_t)b*SN + q0;
    float bo0 = bo[wv*32 + col], bo1 = bo[wv*32 + 16 + col];
    #pragma unroll
    for (int qg = 0; qg < 4; qg++){
        #pragma unroll
        for (int r = 0; r < 4; r++){
            int row = qg*16 + quad*4 + r;
            float x0 = y[qg][0][r] + bo0 + b2f(res[(growb + row)*EN + wv*32 + col]);
            float x1 = y[qg][1][r] + bo1 + b2f(res[(growb + row)*EN + wv*32 + 16 + col]);
            y[qg][0][r] = x0; y[qg][1][r] = x1;
            float s1 = x0 + x1, s2 = x0*x0 + x1*x1;
            #pragma unroll
            for (int m = 1; m <= 8; m <<= 1){
                s1 += __shfl_xor(s1, m);
                s2 += __shfl_xor(s2, m);
            }
            if (col == 0){
                lnw[wv][row][0] = s1;
                lnw[wv][row][1] = s2;
            }
        }
    }
    __syncthreads();

    // ---- LN1 finalize + store ----
    float g0 = gamma[wv*32 + col],      g1v = gamma[wv*32 + 16 + col];
    float e0 = beta[wv*32 + col],       e1v = beta[wv*32 + 16 + col];
    #pragma unroll
    for (int qg = 0; qg < 4; qg++){
        #pragma unroll
        for (int r = 0; r < 4; r++){
            int row = qg*16 + quad*4 + r;
            float S1 = 0.f, S2 = 0.f;
            #pragma unroll
            for (int w = 0; w < 8; w++){ S1 += lnw[w][row][0]; S2 += lnw[w][row][1]; }
            float mu = S1 * (1.f/256.f);
            float rs = rsqrtf(S2 * (1.f/256.f) - mu*mu + 1e-5f);
            out[(growb + row)*EN + wv*32 + col]      = f2b((y[qg][0][r]-mu)*rs*g0 + e0);
            out[(growb + row)*EN + wv*32 + 16 + col] = f2b((y[qg][1][r]-mu)*rs*g1v + e1v);
        }
    }
}

// ---------------------------------------------------------------------------
extern "C" void kernel_launch(void* const* d_in, const int* in_sizes, int n_in,
                              void* d_out, int out_size, void* d_ws, size_t ws_size,
                              hipStream_t stream)
{
    (void)in_sizes; (void)n_in; (void)out_size; (void)ws_size;
    const float* src  = (const float*)d_in[0];
    const float* pos  = (const float*)d_in[1];
    const float* Wpos = (const float*)d_in[2];
    const float* bpos = (const float*)d_in[3];
    const float* ls   = (const float*)d_in[4];
    const float* os   = (const float*)d_in[5];
    const float* Wv   = (const float*)d_in[6];
    const float* bv   = (const float*)d_in[7];
    const float* Wo   = (const float*)d_in[8];
    const float* bo   = (const float*)d_in[9];
    const float* W1   = (const float*)d_in[10];
    const float* b1   = (const float*)d_in[11];
    const float* W2   = (const float*)d_in[12];
    const float* b2   = (const float*)d_in[13];
    const float* g1   = (const float*)d_in[14];
    const float* be1  = (const float*)d_in[15];
    const float* g2   = (const float*)d_in[16];
    const float* be2  = (const float*)d_in[17];

    char* w = (char*)d_ws;
    bf16_t* xkb  = (bf16_t*)(w);                         // 2 MB [B,S,64]
    bf16_t* xqb  = (bf16_t*)(w + ( 2u<<20));             // 2 MB
    bf16_t* Wvb  = (bf16_t*)(w + ( 4u<<20));             // 128 KB
    bf16_t* Wob  = (bf16_t*)(w + ( 4u<<20) + (1u<<18));  // 128 KB (fragment order)
    bf16_t* W1b  = (bf16_t*)(w + ( 5u<<20));             // 512 KB
    bf16_t* W2b  = (bf16_t*)(w + ( 6u<<20));             // 512 KB
    bf16_t* srcb = (bf16_t*)(w + ( 8u<<20));             // 8 MB (alive thru attn res)
    bf16_t* vtg  = (bf16_t*)(w + (16u<<20));             // 8 MB vfrag
    bf16_t* xws  = (bf16_t*)(w + (24u<<20));             // 8 MB (x = LN1 out)

    prep_kernel<<<dim3(4800), 256, 0, stream>>>(
        src, srcb, Wv, Wvb, Wo, Wob, W1, W1b, W2, W2b,
        pos, Wpos, bpos, ls, xkb, xqb);

    // v = src @ Wv^T + bv  -> fragment-ordered store vfrag[b][eb][k16][lane][8]
    gemm_t<3, bf16_t><<<dim3(BS/64, EN/64), 256, 0, stream>>>(
        srcb, Wvb, bv, (bf16_t*)nullptr, vtg, EN, EN);
    // x = LN1( softmax(..) @ v @ Wo^T + bo + src )   [attn + Wo + LN1 fused,
    // producer/consumer wave-specialized]
    attn_kernel<<<dim3(256), 512, 0, stream>>>(
        xkb, xqb, vtg, os, Wob, bo, srcb, g1, be1, xws);
    // out = LN2( relu(x@W1^T+b1) @ W2^T + b2 + x )   [FFN + LN2 fused, 2 blk/CU]
    ffn_ln_kernel<<<dim3(BS/32), 512, 0, stream>>>(
        xws, W1b, b1, W2b, b2, g2, be2, (float*)d_out);
}

// Round 14
// 225.737 us; speedup vs baseline: 1.8267x; 1.8267x over previous
//
#include <hip/hip_runtime.h>
#include <stdint.h>

#define BN 4
#define SN 4096
#define EN 256
#define PN 32
#define FN 1024
#define BS (BN*SN)   // 16384
#define PAUG 64      // 32 xs chans + aug (+ zero pad to 64)

typedef uint16_t bf16_t;
typedef short v4s  __attribute__((ext_vector_type(4)));
typedef short v8s  __attribute__((ext_vector_type(8)));
typedef __bf16 bf16x8 __attribute__((ext_vector_type(8)));
typedef float v4f   __attribute__((ext_vector_type(4)));
typedef float v16f  __attribute__((ext_vector_type(16)));

#define MFMA16(a,b,c) __builtin_amdgcn_mfma_f32_16x16x32_bf16(a,b,c,0,0,0)
#define MFMA32(a,b,c) __builtin_amdgcn_mfma_f32_32x32x16_bf16(a,b,c,0,0,0)

__device__ __forceinline__ float b2f(bf16_t x){
    uint32_t u = ((uint32_t)x) << 16; float f; __builtin_memcpy(&f, &u, 4); return f;
}
__device__ __forceinline__ bf16_t f2b(float f){
    uint32_t u; __builtin_memcpy(&u, &f, 4);
    u += 0x7FFFu + ((u >> 16) & 1u);           // RNE
    return (bf16_t)(u >> 16);
}
__device__ __forceinline__ bf16x8 ldb8(const bf16_t* p){
    v8s r = *(const v8s*)p; return __builtin_bit_cast(bf16x8, r);
}
// 8-B-aligned load pair (for LDS rows with odd 8-B stride -> 2-way-free banks)
__device__ __forceinline__ bf16x8 ldb8u(const bf16_t* p){
    v4s lo = *(const v4s*)p;
    v4s hi = *(const v4s*)(p + 4);
    v8s r = __builtin_shufflevector(lo, hi, 0,1,2,3,4,5,6,7);
    return __builtin_bit_cast(bf16x8, r);
}
__device__ __forceinline__ float ldsc(const float* p){ return *p; }
__device__ __forceinline__ float ldsc(const bf16_t* p){ return b2f(*p); }
__device__ __forceinline__ void stsc(float* p, float v){ *p = v; }
__device__ __forceinline__ void stsc(bf16_t* p, float v){ *p = f2b(v); }

#if __has_builtin(__builtin_amdgcn_exp2f)
__device__ __forceinline__ float fexp2(float x){ return __builtin_amdgcn_exp2f(x); }
#else
__device__ __forceinline__ float fexp2(float x){ return exp2f(x); }
#endif

#if __has_builtin(__builtin_amdgcn_cvt_pk_bf16_f32)
typedef __bf16 bf16x2 __attribute__((ext_vector_type(2)));
__device__ __forceinline__ uint32_t pkbf16(float a, float b){
    bf16x2 r = __builtin_amdgcn_cvt_pk_bf16_f32(a, b);
    return __builtin_bit_cast(uint32_t, r);
}
#else
__device__ __forceinline__ uint32_t pkbf16(float a, float b){
    return (uint32_t)f2b(a) | ((uint32_t)f2b(b) << 16);
}
#endif

typedef const __attribute__((address_space(1))) uint32_t* glds_gp;
typedef __attribute__((address_space(3))) uint32_t* glds_lp;
__device__ __forceinline__ void glds16(const bf16_t* g, bf16_t* l){
    __builtin_amdgcn_global_load_lds((glds_gp)g, (glds_lp)l, 16, 0, 0);
}

// ---------------------------------------------------------------------------
// prep: (a) src fp32->bf16, (b) weight cvts (Wo -> MFMA16-B FRAGMENT order),
// (c) posxs. One launch.
// ---------------------------------------------------------------------------
__global__ __launch_bounds__(256) void prep_kernel(
    const float* __restrict__ src, bf16_t* __restrict__ srcb,
    const float* __restrict__ Wv, bf16_t* __restrict__ Wvb,
    const float* __restrict__ Wo, bf16_t* __restrict__ Wob,
    const float* __restrict__ W1, bf16_t* __restrict__ W1b,
    const float* __restrict__ W2, bf16_t* __restrict__ W2b,
    const float* __restrict__ pos, const float* __restrict__ Wp,
    const float* __restrict__ bp,  const float* __restrict__ lsp,
    bf16_t* __restrict__ xk, bf16_t* __restrict__ xq)
{
    __shared__ float Wsh[PN*PN];
    __shared__ float bsh[PN];
    int bid = blockIdx.x;
    int tid = threadIdx.x;

    if (bid < 4736){
        const float* sp; bf16_t* dp; int off;
        if (bid < 4096){ sp = src; dp = srcb; off = (bid*256 + tid)*4; }
        else {
            int i = ((bid - 4096)*256 + tid)*4;
            if      (i <  65536){ sp=Wv; dp=Wvb; off=i; }
            else if (i < 131072){
                // Wo -> fragment order
                int idx = i - 65536;
                float4 f = *(const float4*)(Wo + idx);
                v4s o;
                o.x = (short)f2b(f.x); o.y = (short)f2b(f.y);
                o.z = (short)f2b(f.z); o.w = (short)f2b(f.w);
                int n = idx >> 8, k = idx & 255;
                int dst = (((n>>4)*8 + (k>>5))*64 + (((k>>3)&3)*16 + (n&15)))*8 + (k&7);
                *(v4s*)(Wob + dst) = o;
                return;
            }
            else if (i < 393216){ sp=W1; dp=W1b; off=i-131072; }
            else                { sp=W2; dp=W2b; off=i-393216; }
        }
        float4 f = *(const float4*)(sp + off);
        v4s o;
        o.x = (short)f2b(f.x); o.y = (short)f2b(f.y);
        o.z = (short)f2b(f.z); o.w = (short)f2b(f.w);
        *(v4s*)(dp + off) = o;
        return;
    }

    int pb = bid - 4736;          // 0..63
    int b  = pb >> 4;
    int s  = (pb & 15)*256 + tid;

    for (int i = tid; i < PN*PN; i += 256) Wsh[i] = Wp[i];
    if (tid < PN) bsh[tid] = bp[tid];
    __syncthreads();

    float inv_ls = 1.0f / lsp[0];
    const float c1f = 1.4426950408889634f;

    float col[PN];
    #pragma unroll
    for (int p = 0; p < PN; p++) col[p] = pos[((size_t)b*PN + p)*SN + s];

    uint16_t xb[PN], qb[PN];
    float sq = 0.f;
    #pragma unroll 4
    for (int o = 0; o < PN; o++){
        float pe = bsh[o];
        #pragma unroll
        for (int p = 0; p < PN; p++) pe += col[p] * Wsh[o*PN + p];
        float pv = pe * inv_ls;
        uint16_t h = f2b(pv);
        xb[o] = h;
        qb[o] = f2b(c1f * pv);
        float xr = b2f(h);
        sq += xr * xr;
    }

    size_t base = ((size_t)b*SN + s) * PAUG;
    v8s pk[8];
    #pragma unroll
    for (int c = 0; c < 4; c++)
        #pragma unroll
        for (int j = 0; j < 8; j++) ((short*)&pk[c])[j] = (short)xb[c*8 + j];
    #pragma unroll
    for (int c = 4; c < 8; c++)
        #pragma unroll
        for (int j = 0; j < 8; j++) ((short*)&pk[c])[j] = 0;
    ((short*)&pk[4])[0] = (short)f2b(-0.5f * sq);
    ((short*)&pk[4])[1] = (short)0x3F80;   // 1.0
    #pragma unroll
    for (int c = 0; c < 8; c++) *(v8s*)(xk + base + c*8) = pk[c];

    #pragma unroll
    for (int c = 0; c < 4; c++)
        #pragma unroll
        for (int j = 0; j < 8; j++) ((short*)&pk[c])[j] = (short)qb[c*8 + j];
    ((short*)&pk[4])[0] = (short)f2b(c1f);
    ((short*)&pk[4])[1] = (short)f2b(-0.5f * sq * c1f);
    #pragma unroll
    for (int c = 0; c < 8; c++) *(v8s*)(xq + base + c*8) = pk[c];
}

// ---------------------------------------------------------------------------
// gemm_t (64x64 tile) -- kept ONLY for the Wv projection (EPI 3: fragment-
// ordered V store, lane-major coalesced epilogue).
// ---------------------------------------------------------------------------
template<int EPI, typename OutT>
__global__ __launch_bounds__(256) void gemm_t(
    const bf16_t* __restrict__ A, const bf16_t* __restrict__ W,
    const float* __restrict__ bias, OutT* __restrict__ out,
    bf16_t* __restrict__ vt, int N, int K)
{
    __shared__ __align__(16) bf16_t At[2][4096];   // 2 x 8 KB
    __shared__ __align__(16) bf16_t Wt[2][4096];   // 2 x 8 KB
    int tid = threadIdx.x;
    int lane = tid & 63, wv = tid >> 6, col = lane & 15, quad = lane >> 4;
    int m0 = blockIdx.x * 64, n0 = blockIdx.y * 64;
    int nck = K >> 6;

    int srow = tid >> 3;                      // 0..31
    int spc  = (tid & 7) ^ (srow & 7);        // swizzled source piece
    const bf16_t* asrc = A + (size_t)(m0 + srow)*K + spc*8;
    const bf16_t* wsrc = W + (size_t)(n0 + srow)*K + spc*8;

    v4f acc[4];
    #pragma unroll
    for (int t = 0; t < 4; t++) acc[t] = (v4f){0.f,0.f,0.f,0.f};

    // stage chunk 0
    glds16(asrc, &At[0][tid*8]);
    glds16(asrc + (size_t)32*K, &At[0][2048 + tid*8]);
    glds16(wsrc, &Wt[0][tid*8]);
    glds16(wsrc + (size_t)32*K, &Wt[0][2048 + tid*8]);
    __syncthreads();

    for (int c = 0; c < nck; c++){
        int cb = c & 1;
        if (c + 1 < nck){
            glds16(asrc + (c+1)*64, &At[cb^1][tid*8]);
            glds16(asrc + (size_t)32*K + (c+1)*64, &At[cb^1][2048 + tid*8]);
            glds16(wsrc + (c+1)*64, &Wt[cb^1][tid*8]);
            glds16(wsrc + (size_t)32*K + (c+1)*64, &Wt[cb^1][2048 + tid*8]);
        }
        #pragma unroll
        for (int kc = 0; kc < 2; kc++){
            int pc = ((kc*4 + quad) ^ (col & 7)) * 8;
            bf16x8 a = ldb8(&At[cb][(wv*16 + col)*64 + pc]);
            #pragma unroll
            for (int t = 0; t < 4; t++){
                bf16x8 b = ldb8(&Wt[cb][(t*16 + col)*64 + pc]);
                acc[t] = MFMA16(a, b, acc[t]);
            }
        }
        __syncthreads();
    }

    float bfv[4];
    #pragma unroll
    for (int t = 0; t < 4; t++) bfv[t] = bias[n0 + t*16 + col];

    if constexpr (EPI == 3){
        __shared__ uint16_t Tsh[64*74];
        #pragma unroll
        for (int r = 0; r < 4; r++)
            #pragma unroll
            for (int t = 0; t < 4; t++)
                Tsh[(wv*16 + quad*4 + r)*74 + t*16 + col] = f2b(acc[t][r] + bfv[t]);
        __syncthreads();
        int e = tid & 63, sc = tid >> 6;       // lane-major e (coalesced)
        int b = m0 >> 12;
        int sbat = m0 & (SN-1);
        int eb   = (n0 + e) >> 5;
        int l31e = (n0 + e) & 31;
        int k16  = (sbat >> 4) + sc;
        v8s p0, p1;
        #pragma unroll
        for (int i = 0; i < 8; i++) ((short*)&p0)[i] = (short)Tsh[(sc*16 + i)*74 + e];
        #pragma unroll
        for (int i = 0; i < 8; i++) ((short*)&p1)[i] = (short)Tsh[(sc*16 + 8 + i)*74 + e];
        bf16_t* dst = vt + ((((size_t)b*8 + eb)*256 + k16)*64 + l31e)*8;
        *(v8s*)dst = p0;              // half 0 (keys s&15 in 0..7)
        *(v8s*)(dst + 256) = p1;      // half 1 (keys s&15 in 8..15), +32 lanes
    } else {
        #pragma unroll
        for (int r = 0; r < 4; r++){
            int row = m0 + wv*16 + quad*4 + r;
            #pragma unroll
            for (int t = 0; t < 4; t++){
                float y = acc[t][r] + bfv[t];
                if constexpr (EPI == 1) y = fmaxf(y, 0.f);
                stsc(out + (size_t)row*N + n0 + t*16 + col, y);
            }
        }
    }
}

// ---------------------------------------------------------------------------
// ffn_ln v2 (verified round 12): out = LN2( relu(x@W1^T+b1) @ W2^T + b2 + x ).
// 32 rows/block, grid 512 (2 blocks/CU), single-buffered weight chunks.
// ---------------------------------------------------------------------------
__global__ __launch_bounds__(512, 4) void ffn_ln_kernel(
    const bf16_t* __restrict__ x,  const bf16_t* __restrict__ W1b,
    const float* __restrict__ b1,  const bf16_t* __restrict__ W2b,
    const float* __restrict__ b2,  const float* __restrict__ gamma,
    const float* __restrict__ beta, float* __restrict__ out)
{
    __shared__ __align__(16) bf16_t W1c[16384];  // 32 KB [kgrp s][64 h][8 pc]
    __shared__ __align__(16) bf16_t W2c[16384];  // 32 KB [ngrp s2][64 n][8 pc]
    __shared__ __align__(16) bf16_t Hs[32*68];   // 4.25 KB
    __shared__ float b1sh[1024];                 // 4 KB
    __shared__ float lnb[4][32][2];              // 1 KB

    int tid  = threadIdx.x;
    int lane = tid & 63;
    int wv   = tid >> 6;         // 0..7
    int col  = lane & 15;
    int quad = lane >> 4;
    int mw   = wv >> 2;          // 0..1 -> rows mw*16..+16
    int nw   = wv & 3;           // 0..3
    int m0   = blockIdx.x * 32;

    b1sh[tid]       = b1[tid];
    b1sh[512 + tid] = b1[512 + tid];

    const bf16_t* xrow = x + (size_t)(m0 + mw*16 + col)*EN + quad*8;
    bf16x8 xr[8];
    #pragma unroll
    for (int kk = 0; kk < 8; kk++) xr[kk] = ldb8(xrow + kk*32);

    float b2v[4], gv[4], bev[4];
    #pragma unroll
    for (int t2 = 0; t2 < 4; t2++){
        int nn = nw*64 + t2*16 + col;
        b2v[t2] = b2[nn]; gv[t2] = gamma[nn]; bev[t2] = beta[nn];
    }

    v4f acc[4];
    #pragma unroll
    for (int t2 = 0; t2 < 4; t2++) acc[t2] = (v4f){0.f,0.f,0.f,0.f};

    int wr  = tid >> 3;          // 0..63
    int pp  = tid & 7;
    int swz = (pp ^ (wr & 7)) * 8;

    #pragma unroll 1
    for (int c = 0; c < 16; c++){
        #pragma unroll
        for (int s = 0; s < 4; s++)
            glds16(W1b + (size_t)(c*64 + wr)*256 + s*64 + swz,
                   &W1c[s*4096 + tid*8]);
        #pragma unroll
        for (int s2 = 0; s2 < 4; s2++)
            glds16(W2b + (size_t)(s2*64 + wr)*1024 + c*64 + swz,
                   &W2c[s2*4096 + tid*8]);
        asm volatile("s_waitcnt vmcnt(0)" ::: "memory");
        __builtin_amdgcn_s_barrier();
        __builtin_amdgcn_sched_barrier(0);

        int hl = nw*16 + col;
        v4f hacc = (v4f){0.f,0.f,0.f,0.f};
        #pragma unroll
        for (int kk = 0; kk < 8; kk++){
            bf16x8 b = ldb8(&W1c[(kk>>1)*4096 + hl*64
                             + ((((kk&1)*4 + quad) ^ (hl & 7))*8)]);
            hacc = MFMA16(xr[kk], b, hacc);
        }
        float bb = b1sh[c*64 + hl];
        #pragma unroll
        for (int r = 0; r < 4; r++)
            Hs[(mw*16 + quad*4 + r)*68 + hl] = f2b(fmaxf(hacc[r] + bb, 0.f));
        asm volatile("s_waitcnt lgkmcnt(0)" ::: "memory");
        __builtin_amdgcn_s_barrier();
        __builtin_amdgcn_sched_barrier(0);

        #pragma unroll
        for (int kk2 = 0; kk2 < 2; kk2++){
            bf16x8 a2 = ldb8u(&Hs[(mw*16 + col)*68 + kk2*32 + quad*8]);
            #pragma unroll
            for (int t2 = 0; t2 < 4; t2++){
                int nn = nw*64 + t2*16 + col;
                bf16x8 bfr = ldb8(&W2c[(nn>>6)*4096 + (nn&63)*64
                                  + (((kk2*4 + quad) ^ (col & 7))*8)]);
                acc[t2] = MFMA16(a2, bfr, acc[t2]);
            }
        }
        asm volatile("s_waitcnt lgkmcnt(0)" ::: "memory");
        __builtin_amdgcn_s_barrier();
    }

    // ---- fused LN2 epilogue ----
    float v[4][4];
    float s1[4], s2[4];
    #pragma unroll
    for (int r = 0; r < 4; r++){ s1[r] = 0.f; s2[r] = 0.f; }
    #pragma unroll
    for (int r = 0; r < 4; r++){
        int row = m0 + mw*16 + quad*4 + r;
        #pragma unroll
        for (int t2 = 0; t2 < 4; t2++){
            int nn = nw*64 + t2*16 + col;
            float xv = acc[t2][r] + b2v[t2] + b2f(x[(size_t)row*EN + nn]);
            v[t2][r] = xv; s1[r] += xv; s2[r] += xv*xv;
        }
    }
    #pragma unroll
    for (int r = 0; r < 4; r++){
        #pragma unroll
        for (int m = 1; m <= 8; m <<= 1){
            s1[r] += __shfl_xor(s1[r], m);
            s2[r] += __shfl_xor(s2[r], m);
        }
    }
    if (col == 0){
        #pragma unroll
        for (int r = 0; r < 4; r++){
            int rl = mw*16 + quad*4 + r;
            lnb[nw][rl][0] = s1[r];
            lnb[nw][rl][1] = s2[r];
        }
    }
    __syncthreads();
    #pragma unroll
    for (int r = 0; r < 4; r++){
        int rl  = mw*16 + quad*4 + r;
        int row = m0 + rl;
        float S1 = lnb[0][rl][0] + lnb[1][rl][0] + lnb[2][rl][0] + lnb[3][rl][0];
        float S2 = lnb[0][rl][1] + lnb[1][rl][1] + lnb[2][rl][1] + lnb[3][rl][1];
        float mu = S1 * (1.f/256.f);
        float rs = rsqrtf(S2 * (1.f/256.f) - mu*mu + 1e-5f);
        #pragma unroll
        for (int t2 = 0; t2 < 4; t2++){
            int nn = nw*64 + t2*16 + col;
            out[(size_t)row*EN + nn] = (v[t2][r] - mu)*rs*gv[t2] + bev[t2];
        }
    }
}

// ---------------------------------------------------------------------------
// Attention (round-11 structure, verified 70.0 us / VGPR 92 / no spill):
// chunk 256, raw barriers, parity dbuf, fused Wo+res+LN1 epilogue with
// hoisted wf0. Reverted from the round-13 producer/consumer experiment
// (register budget > 128 -> 557 MB scratch spills).
// ---------------------------------------------------------------------------
__global__ __launch_bounds__(512, 2) void attn_kernel(
    const bf16_t* __restrict__ xk, const bf16_t* __restrict__ xq,
    const bf16_t* __restrict__ vf, const float* __restrict__ osp,
    const bf16_t* __restrict__ wof, const float* __restrict__ bo,
    const bf16_t* __restrict__ res, const float* __restrict__ gamma,
    const float* __restrict__ beta, bf16_t* __restrict__ out)
{
    __shared__ __align__(16) bf16_t Wtb[2][64*260];   // 65 KB
    __shared__ __align__(16) bf16_t Qs[64*64];        // 8 KB
    __shared__ __align__(16) bf16_t Osh[64*256];      // 32 KB (O tile, swizzled)
    __shared__ float densh[8][64];                    // 2 KB
    __shared__ float dent[64];
    __shared__ float lnw[8][64][2];                   // 4 KB

    int tid  = threadIdx.x;
    int lane = tid & 63;
    int wv   = tid >> 6;          // 0..7
    int col  = lane & 15;
    int quad = lane >> 4;
    int l31  = lane & 31;
    int half = lane >> 5;

    int bid = blockIdx.x;                    // 0..255
    int b   = (bid & 7) >> 1;
    int qi  = ((bid >> 3) << 1) | (bid & 1); // 0..63
    int q0  = qi * 64;

    float k2 = 1.4426950408889634f * osp[0];

    const bf16_t* xkb = xk + (size_t)b * SN * PAUG;
    const bf16_t* xqb = xq + (size_t)b * SN * PAUG;
    const bf16_t* vfb = vf + (((size_t)b*8 + wv)*256)*512 + lane*8;

    // stage Q tile: piece-swizzled SOURCE, linear dest
    {
        int qrow = tid >> 3;                 // 0..63
        int qpc  = (tid & 7) ^ (qrow & 7);
        glds16(xqb + (size_t)(q0 + qrow)*PAUG + qpc*8, &Qs[tid*8]);
    }

    v16f acc[2];
    #pragma unroll
    for (int qg = 0; qg < 2; qg++)
        #pragma unroll
        for (int i = 0; i < 16; i++) acc[qg][i] = 0.f;
    float den[4] = {0.f, 0.f, 0.f, 0.f};
    const v4f zero = (v4f){0.f,0.f,0.f,0.f};

    // kf prologue (chunk 0): this wave's 32 keys, 2 kg x 2 paug-halves
    bf16x8 kf[2][2];
    #pragma unroll
    for (int kg = 0; kg < 2; kg++)
        #pragma unroll
        for (int h = 0; h < 2; h++)
            kf[kg][h] = ldb8(xkb + (size_t)(wv*32 + kg*16 + col)*PAUG + h*32 + quad*8);

    __syncthreads();   // Qs staged

    for (int c = 0; c < 16; c++){
        int cb = c & 1;
        // issue V(c): 16 coalesced b128 into regs
        bf16x8 vr[16];
        #pragma unroll
        for (int sk = 0; sk < 16; sk++)
            vr[sk] = ldb8(vfb + (size_t)(c*16 + sk)*512);

        // QK + exp: this wave's 32-key slice x 64 q of chunk c
        #pragma unroll
        for (int qg = 0; qg < 2; qg++){
            #pragma unroll
            for (int g2 = 0; g2 < 2; g2++){
                int qr = qg*32 + g2*16 + col;
                bf16x8 qa = ldb8(&Qs[qr*64 + ((quad    ) ^ (col & 7))*8]);
                bf16x8 qb = ldb8(&Qs[qr*64 + ((4 + quad) ^ (col & 7))*8]);
                #pragma unroll
                for (int kg = 0; kg < 2; kg++){
                    v4f st = MFMA16(kf[kg][0], qa, zero);
                    st = MFMA16(kf[kg][1], qb, st);
                    #pragma unroll
                    for (int rp = 0; rp < 2; rp++){
                        float w0 = fexp2(fmaf(k2, fexp2(st[rp*2+0]), -k2));
                        float w1 = fexp2(fmaf(k2, fexp2(st[rp*2+1]), -k2));
                        den[qg*2+g2] += w0 + w1;
                        *(uint32_t*)&Wtb[cb][qr*260 + wv*32 + kg*16 + quad*4 + rp*2]
                            = pkbf16(w0, w1);
                    }
                }
            }
        }

        // prefetch kf(c+1) (stays in flight across raw barrier)
        if (c + 1 < 16){
            #pragma unroll
            for (int kg = 0; kg < 2; kg++)
                #pragma unroll
                for (int h = 0; h < 2; h++)
                    kf[kg][h] = ldb8(xkb + (size_t)((c+1)*256 + wv*32 + kg*16 + col)*PAUG
                                     + h*32 + quad*8);
        }

        asm volatile("s_waitcnt lgkmcnt(0)" ::: "memory");
        __builtin_amdgcn_s_barrier();
        __builtin_amdgcn_sched_barrier(0);

        // PV chunk c: this wave's 32-e slice, 2 qg x 16 MFMA32 over k=256
        #pragma unroll
        for (int qg = 0; qg < 2; qg++){
            #pragma unroll
            for (int sk4 = 0; sk4 < 4; sk4++){
                bf16x8 af[4];
                #pragma unroll
                for (int j = 0; j < 4; j++)
                    af[j] = ldb8u(&Wtb[cb][(qg*32 + l31)*260 + (sk4*4 + j)*16 + half*8]);
                #pragma unroll
                for (int j = 0; j < 4; j++)
                    acc[qg] = MFMA32(af[j], vr[sk4*4 + j], acc[qg]);
            }
        }
    }

    // ---- hoist Wo b0-set fragment loads (L2 latency hides under den+Osh) ----
    bf16x8 wf0[8];
    #pragma unroll
    for (int kc = 0; kc < 8; kc++)
        wf0[kc] = ldb8(wof + (size_t)(((wv*2+0)*8 + kc)*64 + lane)*8);

    // ---- den reduce ----
    #pragma unroll
    for (int d = 0; d < 4; d++){
        den[d] += __shfl_xor(den[d], 16);
        den[d] += __shfl_xor(den[d], 32);
    }
    if (lane < 16){
        #pragma unroll
        for (int qg = 0; qg < 2; qg++)
            #pragma unroll
            for (int g2 = 0; g2 < 2; g2++)
                densh[wv][qg*32 + g2*16 + lane] = den[qg*2+g2];
    }
    __syncthreads();
    if (tid < 64){
        float s = 0.f;
        #pragma unroll
        for (int w = 0; w < 8; w++) s += densh[w][tid];
        dent[tid] = 1.f / s;
    }
    __syncthreads();

    // ---- O -> LDS (write-side XOR piece swizzle) ----
    #pragma unroll
    for (int qg = 0; qg < 2; qg++){
        #pragma unroll
        for (int rg = 0; rg < 16; rg++){
            int qrow = qg*32 + (rg & 3) + 8*(rg >> 2) + 4*half;
            int e = wv*32 + l31;
            int g = e >> 3;
            Osh[qrow*256 + ((g ^ (qrow & 7))*8) + (e & 7)] = f2b(acc[qg][rg] * dent[qrow]);
        }
    }
    __syncthreads();

    // ---- y1 = O @ Wo^T : wave wv -> n-slice [wv*32, wv*32+32), K=256 ----
    v4f y[4][2];
    #pragma unroll
    for (int qg = 0; qg < 4; qg++)
        #pragma unroll
        for (int t = 0; t < 2; t++) y[qg][t] = (v4f){0.f,0.f,0.f,0.f};

    #pragma unroll
    for (int kc = 0; kc < 8; kc++){
        bf16x8 b1 = ldb8(wof + (size_t)(((wv*2+1)*8 + kc)*64 + lane)*8);
        #pragma unroll
        for (int qg = 0; qg < 4; qg++){
            bf16x8 a = ldb8(&Osh[(qg*16 + col)*256 + (((kc*4 + quad) ^ (col & 7))*8)]);
            y[qg][0] = MFMA16(a, wf0[kc], y[qg][0]);
            y[qg][1] = MFMA16(a, b1, y[qg][1]);
        }
    }

    // ---- bias + residual + LN1 partials ----
    size_t growb = (size_t)b*SN + q0;
    float bo0 = bo[wv*32 + col], bo1 = bo[wv*32 + 16 + col];
    #pragma unroll
    for (int qg = 0; qg < 4; qg++){
        #pragma unroll
        for (int r = 0; r < 4; r++){
            int row = qg*16 + quad*4 + r;
            float x0 = y[qg][0][r] + bo0 + b2f(res[(growb + row)*EN + wv*32 + col]);
            float x1 = y[qg][1][r] + bo1 + b2f(res[(growb + row)*EN + wv*32 + 16 + col]);
            y[qg][0][r] = x0; y[qg][1][r] = x1;
            float s1 = x0 + x1, s2 = x0*x0 + x1*x1;
            #pragma unroll
            for (int m = 1; m <= 8; m <<= 1){
                s1 += __shfl_xor(s1, m);
                s2 += __shfl_xor(s2, m);
            }
            if (col == 0){
                lnw[wv][row][0] = s1;
                lnw[wv][row][1] = s2;
            }
        }
    }
    __syncthreads();

    // ---- LN1 finalize + store ----
    float g0 = gamma[wv*32 + col],      g1v = gamma[wv*32 + 16 + col];
    float e0 = beta[wv*32 + col],       e1v = beta[wv*32 + 16 + col];
    #pragma unroll
    for (int qg = 0; qg < 4; qg++){
        #pragma unroll
        for (int r = 0; r < 4; r++){
            int row = qg*16 + quad*4 + r;
            float S1 = 0.f, S2 = 0.f;
            #pragma unroll
            for (int w = 0; w < 8; w++){ S1 += lnw[w][row][0]; S2 += lnw[w][row][1]; }
            float mu = S1 * (1.f/256.f);
            float rs = rsqrtf(S2 * (1.f/256.f) - mu*mu + 1e-5f);
            out[(growb + row)*EN + wv*32 + col]      = f2b((y[qg][0][r]-mu)*rs*g0 + e0);
            out[(growb + row)*EN + wv*32 + 16 + col] = f2b((y[qg][1][r]-mu)*rs*g1v + e1v);
        }
    }
}

// ---------------------------------------------------------------------------
extern "C" void kernel_launch(void* const* d_in, const int* in_sizes, int n_in,
                              void* d_out, int out_size, void* d_ws, size_t ws_size,
                              hipStream_t stream)
{
    (void)in_sizes; (void)n_in; (void)out_size; (void)ws_size;
    const float* src  = (const float*)d_in[0];
    const float* pos  = (const float*)d_in[1];
    const float* Wpos = (const float*)d_in[2];
    const float* bpos = (const float*)d_in[3];
    const float* ls   = (const float*)d_in[4];
    const float* os   = (const float*)d_in[5];
    const float* Wv   = (const float*)d_in[6];
    const float* bv   = (const float*)d_in[7];
    const float* Wo   = (const float*)d_in[8];
    const float* bo   = (const float*)d_in[9];
    const float* W1   = (const float*)d_in[10];
    const float* b1   = (const float*)d_in[11];
    const float* W2   = (const float*)d_in[12];
    const float* b2   = (const float*)d_in[13];
    const float* g1   = (const float*)d_in[14];
    const float* be1  = (const float*)d_in[15];
    const float* g2   = (const float*)d_in[16];
    const float* be2  = (const float*)d_in[17];

    char* w = (char*)d_ws;
    bf16_t* xkb  = (bf16_t*)(w);                         // 2 MB [B,S,64]
    bf16_t* xqb  = (bf16_t*)(w + ( 2u<<20));             // 2 MB
    bf16_t* Wvb  = (bf16_t*)(w + ( 4u<<20));             // 128 KB
    bf16_t* Wob  = (bf16_t*)(w + ( 4u<<20) + (1u<<18));  // 128 KB (fragment order)
    bf16_t* W1b  = (bf16_t*)(w + ( 5u<<20));             // 512 KB
    bf16_t* W2b  = (bf16_t*)(w + ( 6u<<20));             // 512 KB
    bf16_t* srcb = (bf16_t*)(w + ( 8u<<20));             // 8 MB (alive thru attn res)
    bf16_t* vtg  = (bf16_t*)(w + (16u<<20));             // 8 MB vfrag
    bf16_t* xws  = (bf16_t*)(w + (24u<<20));             // 8 MB (x = LN1 out)

    prep_kernel<<<dim3(4800), 256, 0, stream>>>(
        src, srcb, Wv, Wvb, Wo, Wob, W1, W1b, W2, W2b,
        pos, Wpos, bpos, ls, xkb, xqb);

    // v = src @ Wv^T + bv  -> fragment-ordered store vfrag[b][eb][k16][lane][8]
    gemm_t<3, bf16_t><<<dim3(BS/64, EN/64), 256, 0, stream>>>(
        srcb, Wvb, bv, (bf16_t*)nullptr, vtg, EN, EN);
    // x = LN1( softmax(..) @ v @ Wo^T + bo + src )   [attn + Wo + LN1 fused]
    attn_kernel<<<dim3(256), 512, 0, stream>>>(
        xkb, xqb, vtg, os, Wob, bo, srcb, g1, be1, xws);
    // out = LN2( relu(x@W1^T+b1) @ W2^T + b2 + x )   [FFN + LN2 fused, 2 blk/CU]
    ffn_ln_kernel<<<dim3(BS/32), 512, 0, stream>>>(
        xws, W1b, b1, W2b, b2, g2, be2, (float*)d_out);
}